// Round 7
// baseline (198.885 us; speedup 1.0000x reference)
//
#include <hip/hip_runtime.h>
#include <cmath>

// Problem constants (fixed by setup_inputs)
constexpr int NN = 2;       // batch
constexpr int LL = 2048;    // sequence
constexpr int HH = 8;       // heads
constexpr int EE = 32;      // feature dim == value dim
constexpr int CC = 64;      // chunk length
constexpr int NCH = LL / CC;       // 32 chunks per (n,h)
constexpr int NB  = NN * HH * NCH; // 512 blocks
constexpr int BWD = 10;     // softmax bandwidth
constexpr float EPSF = 1e-6f;
// ws record per chunk: S1[32*32], k1[32], S2[32*32], k2[32] (floats)
constexpr int REC  = 2 * (EE * EE + EE);   // 2112 floats = 528 float4
constexpr int REC4 = REC / 4;              // 528
constexpr int OFF_S1 = 0, OFF_K1 = 1024, OFF_S2 = 1056, OFF_K2 = 2080;
constexpr int SK = EE + 4;   // 36: float2/float4-aligned row stride
constexpr int SP = EE + 1;   // 33: scalar row stride (2-way = free)
constexpr int SB = EE + 2;   // 34: even stride for Bnd (aligned float2 reads)

__device__ __forceinline__ float elu1(float x) {
    return x > 0.f ? x + 1.f : __expf(x);   // elu(x)+1
}

// ---------------- Kernel 1: per-chunk state sums -> ws -----------------------
// one block per (n,h,chunk); 1024 threads (8 waves/SIMD with 2 blocks/CU)
__global__ __launch_bounds__(1024, 8) void chunksum_kernel(
    const float* __restrict__ Kin, const float* __restrict__ Vin,
    const float* __restrict__ KLin, float* __restrict__ ws)
{
    __shared__ float K1n[CC][SK];
    __shared__ float K2n[CC][SK];
    __shared__ float Vs [CC][SK];

    const int b  = blockIdx.x;
    const int c  = b & (NCH - 1);
    const int nh = b >> 5;
    const int t  = threadIdx.x;
    const int lane = t & 31;
    const int hw   = t >> 5;    // 0..31 half-waves

    // phase 1: feature map + normalize (half-wave per row, 2 rows each)
    for (int r = hw; r < CC; r += 32) {
        const int l = c * CC + r;
        const int base = ((nh >> 3) * LL + l) * HH * EE + (nh & 7) * EE + lane;
        const float k    = Kin[base];
        const float v    = Vin[base];
        const float klen = KLin[(nh >> 3) * LL + l];
        const float f1 = elu1(k);
        const float k1v = f1 * klen;
        const float k2v = f1 * f1 * klen;
        float s1 = k1v, s2 = k2v;
        #pragma unroll
        for (int m = 1; m < 32; m <<= 1) {
            s1 += __shfl_xor(s1, m, 32);
            s2 += __shfl_xor(s2, m, 32);
        }
        K1n[r][lane] = k1v / s1;
        K2n[r][lane] = k2v / s2;
        Vs [r][lane] = v;
    }
    __syncthreads();

    // phase 2: S[e][d] = sum_j K[j][e]*V[j][d]; thread = (e = t>>5, d = t&31)
    // ascending-j scalar order => bit-identical ws entries vs R5/R6.
    const int e = t >> 5;           // 0..31
    const int d = t & 31;           // 0..31
    float a1 = 0.f, a2 = 0.f, ks1 = 0.f, ks2 = 0.f;
    for (int j = 0; j < CC; ++j) {
        const float k1 = K1n[j][e];     // 2 addrs/wave -> broadcast, free
        const float k2 = K2n[j][e];
        const float v  = Vs[j][d];      // 2 lanes/addr -> free
        ks1 += k1; ks2 += k2;
        a1 += k1 * v;
        a2 += k2 * v;
    }
    float* wb = ws + (size_t)b * REC;
    wb[OFF_S1 + e * EE + d] = a1;
    wb[OFF_S2 + e * EE + d] = a2;
    if (d == 0) {
        wb[OFF_K1 + e] = ks1;
        wb[OFF_K2 + e] = ks2;
    }
}

// ---------------- Kernel 2: exclusive prefix over chunks per (n,h) -----------
// register scan, proven in R5 (100us -> off the profile)
// grid = 16 groups x 11 blocks of 192 threads (192*11 == REC exactly)
__global__ __launch_bounds__(192) void prefix_kernel(float* __restrict__ ws)
{
    const int g = blockIdx.x / 11;
    const int e = (blockIdx.x % 11) * 192 + threadIdx.x;   // 0..2111
    float* base = ws + (size_t)g * NCH * REC + e;
    float v[NCH];
    #pragma unroll
    for (int c = 0; c < NCH; ++c) v[c] = base[(size_t)c * REC];
    float run = 0.f;
    #pragma unroll
    for (int c = 0; c < NCH; ++c) {
        const float x = v[c];
        base[(size_t)c * REC] = run;
        run += x;
    }
}

// ---------------- Kernel 3: band + linear + single store ---------------------
// one block per (n,h,chunk); 1024 threads. Band phase: half-wave per row,
// scalar stride-33 reads (R5-proven conflict-free). Linear phase: 16-lane
// cluster per row, 2 features/lane. Reads ONLY its own ws record b.
__global__ __launch_bounds__(1024, 8) void fused_kernel(
    const float* __restrict__ Qin, const float* __restrict__ Kin,
    const float* __restrict__ Vin, const float* __restrict__ KLin,
    const float* __restrict__ W1, const float* __restrict__ W2,
    const float* __restrict__ W3, const float* __restrict__ ws,
    float* __restrict__ out)
{
    __shared__ float K1n[CC][SK];          // normalized K, float2-read rows
    __shared__ float K2n[CC][SK];
    __shared__ float Vs [CC + 9][SK];      // rows l0-9 .. l0+63
    __shared__ float Bnd[CC][SB];          // band partial (even stride)
    // raw-K (band phase) and prefix state (linear phase): disjoint lifetimes
    __shared__ __align__(16) union {
        float kr[(CC + 9) * SP];           // 2409 floats
        float sp[REC];                     // 2112 floats, ws-record layout
    } U;

    const int b  = blockIdx.x;
    const int c  = b & (NCH - 1);
    const int nh = b >> 5;
    const int h  = nh & 7;
    const int n  = nh >> 3;
    const int l0 = c * CC;
    const int t  = threadIdx.x;
    const int lane = t & 31;
    const int hw   = t >> 5;       // 0..31

    // own exclusive-prefix record -> registers early (hides under A/B)
    float4 s0 = {0.f, 0.f, 0.f, 0.f};
    {
        const float4* wbv = (const float4*)(ws + (size_t)b * REC);
        if (t < REC4) s0 = wbv[t];       // 528 of 1024 threads
    }

    // ---------------- Phase A: K/V staging + feature map + normalize ---------
    for (int r = hw; r < CC; r += 32) {
        const int l = l0 + r;
        const int base = ((n * LL + l) * HH + h) * EE + lane;
        const float k    = Kin[base];
        const float v    = Vin[base];
        const float klen = KLin[n * LL + l];
        const float f1 = elu1(k);
        const float k1v = f1 * klen;
        const float k2v = f1 * f1 * klen;
        float sk1 = k1v, sk2 = k2v;
        #pragma unroll
        for (int m = 1; m < 32; m <<= 1) {
            sk1 += __shfl_xor(sk1, m, 32);
            sk2 += __shfl_xor(sk2, m, 32);
        }
        K1n[r][lane] = k1v / sk1;
        K2n[r][lane] = k2v / sk2;
        Vs [9 + r][lane] = v;
        U.kr[(9 + r) * SP + lane] = k;
    }
    // previous 9 rows of raw K,V for the band window
    if (t < 9 * 32) {
        const int rr = t >> 5, ln = t & 31;
        const int l = l0 - 9 + rr;
        float kv = 0.f, vv = 0.f;
        if (l >= 0) {
            const int base = ((n * LL + l) * HH + h) * EE + ln;
            kv = Kin[base];
            vv = Vin[base];
        }
        U.kr[rr * SP + ln] = kv;
        Vs[rr][ln] = vv;
    }
    __syncthreads();

    // ---------------- Phase B: banded softmax, half-wave per row -------------
    {
        const float temp = 0.17677669529663687f;   // 1/sqrt(32)
        const float w1v = W1[h * EE + lane];
        for (int r = hw; r < CC; r += 32) {
            const int l = l0 + r;
            const float q = Qin[((n * LL + l) * HH + h) * EE + lane];
            float sarr[BWD];
            #pragma unroll
            for (int jj = 0; jj < BWD; ++jj) {
                const int j = l - (BWD - 1) + jj;
                float s = -INFINITY;
                if (j >= 0) {
                    float p = q * U.kr[(r + jj) * SP + lane];   // 2-way, free
                    #pragma unroll
                    for (int m = 1; m < 32; m <<= 1) p += __shfl_xor(p, m, 32);
                    s = p * temp;
                }
                sarr[jj] = s;
            }
            float mx = -INFINITY;
            #pragma unroll
            for (int jj = 0; jj < BWD; ++jj) mx = fmaxf(mx, sarr[jj]);
            float sum = 0.f;
            #pragma unroll
            for (int jj = 0; jj < BWD; ++jj) {
                const int j = l - (BWD - 1) + jj;
                const float p = (j >= 0) ? __expf(sarr[jj] - mx) : 0.f;
                sarr[jj] = p;
                sum += p;
            }
            const float inv = 1.f / sum;
            float sv = 0.f;
            #pragma unroll
            for (int jj = 0; jj < BWD; ++jj) sv += sarr[jj] * Vs[r + jj][lane];
            Bnd[r][lane] = w1v * (sv * inv);
        }
    }
    __syncthreads();   // all reads of U.kr done

    // publish own prefix record into U.sp (same layout as ws record)
    if (t < REC4) ((float4*)U.sp)[t] = s0;
    __syncthreads();

    const float* S1p = U.sp + OFF_S1;
    const float* S2p = U.sp + OFF_S2;
    const float* k1p = U.sp + OFF_K1;
    const float* k2p = U.sp + OFF_K2;

    // ---------------- Phase C: 16-lane cluster per row, 2 features/lane ------
    const int r   = t >> 4;        // row 0..63
    const int sub = t & 15;
    const int d0  = sub * 2;
    const int l   = l0 + r;

    // Q normalized in registers via width-16 reduce
    float q1r0, q1r1, q2r0, q2r1;
    {
        const float2 q2 = *(const float2*)&Qin[((n * LL + l) * HH + h) * EE + d0];
        const float f0 = elu1(q2.x), f1 = elu1(q2.y);
        float sq1 = f0 + f1;
        float sq2 = f0 * f0 + f1 * f1;
        #pragma unroll
        for (int m = 1; m < 16; m <<= 1) {
            sq1 += __shfl_xor(sq1, m, 16);
            sq2 += __shfl_xor(sq2, m, 16);
        }
        const float i1 = 1.f / sq1, i2 = 1.f / sq2;
        q1r0 = f0 * i1; q1r1 = f1 * i1;
        q2r0 = f0 * f0 * i2; q2r1 = f1 * f1 * i2;
    }

    float acc1x = 0.f, acc1y = 0.f, acc2x = 0.f, acc2y = 0.f;
    float den1 = 0.f, den2 = 0.f;

    // prefix contribution: q broadcast over cluster via width-16 shfl
    #pragma unroll
    for (int who = 0; who < 16; ++who) {
        const float q1a = __shfl(q1r0, who, 16);
        const float q1b = __shfl(q1r1, who, 16);
        const float q2a = __shfl(q2r0, who, 16);
        const float q2b = __shfl(q2r1, who, 16);
        const int e0 = who * 2;
        den1 += q1a * k1p[e0] + q1b * k1p[e0 + 1];
        den2 += q2a * k2p[e0] + q2b * k2p[e0 + 1];
        const float2 sa0 = *(const float2*)&S1p[e0 * EE + d0];       // broadcast
        const float2 sa1 = *(const float2*)&S1p[(e0 + 1) * EE + d0];
        const float2 ta0 = *(const float2*)&S2p[e0 * EE + d0];
        const float2 ta1 = *(const float2*)&S2p[(e0 + 1) * EE + d0];
        acc1x += q1a * sa0.x + q1b * sa1.x;
        acc1y += q1a * sa0.y + q1b * sa1.y;
        acc2x += q2a * ta0.x + q2b * ta1.x;
        acc2y += q2a * ta0.y + q2b * ta1.y;
    }

    // intra-chunk causal: j uniform per iteration -> LDS broadcast, free
    for (int j = 0; j <= r; ++j) {
        const float2 ka = *(const float2*)&K1n[j][d0];
        const float2 la = *(const float2*)&K2n[j][d0];
        float p1 = q1r0 * ka.x + q1r1 * ka.y;
        float p2 = q2r0 * la.x + q2r1 * la.y;
        #pragma unroll
        for (int m = 1; m < 16; m <<= 1) {
            p1 += __shfl_xor(p1, m, 16);
            p2 += __shfl_xor(p2, m, 16);
        }
        den1 += p1;
        den2 += p2;
        const float2 va = *(const float2*)&Vs[9 + j][d0];
        acc1x += p1 * va.x; acc1y += p1 * va.y;
        acc2x += p2 * va.x; acc2y += p2 * va.y;
    }

    const float z1 = 1.f / (den1 + EPSF);
    const float z2 = 1.f / (den2 + EPSF);
    const float2 w2 = *(const float2*)&W2[h * EE + d0];
    const float2 w3 = *(const float2*)&W3[h * EE + d0];
    const float2 bd = *(const float2*)&Bnd[r][d0];      // SB even -> aligned
    float2 o;
    o.x = bd.x + w2.x * acc1x * z1 + w3.x * acc2x * z2;
    o.y = bd.y + w2.y * acc1y * z1 + w3.y * acc2y * z2;
    *(float2*)&out[((n * LL + l) * HH + h) * EE + d0] = o;
}

extern "C" void kernel_launch(void* const* d_in, const int* in_sizes, int n_in,
                              void* d_out, int out_size, void* d_ws, size_t ws_size,
                              hipStream_t stream)
{
    const float* Q  = (const float*)d_in[0];
    const float* K  = (const float*)d_in[1];
    const float* V  = (const float*)d_in[2];
    const float* KL = (const float*)d_in[3];
    const float* W1 = (const float*)d_in[4];
    const float* W2 = (const float*)d_in[5];
    const float* W3 = (const float*)d_in[6];
    float* out = (float*)d_out;
    float* ws  = (float*)d_ws;   // uses NB*REC*4 = ~4.3 MB of scratch

    chunksum_kernel<<<NB,           1024, 0, stream>>>(K, V, KL, ws);
    prefix_kernel  <<<NN * HH * 11,  192, 0, stream>>>(ws);
    fused_kernel   <<<NB,           1024, 0, stream>>>(Q, K, V, KL, W1, W2, W3, ws, out);
}

// Round 8
// 123.920 us; speedup vs baseline: 1.6050x; 1.6050x over previous
//
#include <hip/hip_runtime.h>
#include <cmath>

// Problem constants (fixed by setup_inputs)
constexpr int NN = 2;       // batch
constexpr int LL = 2048;    // sequence
constexpr int HH = 8;       // heads
constexpr int EE = 32;      // feature dim == value dim
constexpr int CC = 64;      // chunk length
constexpr int NCH = LL / CC;       // 32 chunks per (n,h)
constexpr int NB  = NN * HH * NCH; // 512 blocks
constexpr int BWD = 10;     // softmax bandwidth
constexpr float EPSF = 1e-6f;
// ws record per chunk: S1[32*32], k1[32], S2[32*32], k2[32] (floats)
constexpr int REC  = 2 * (EE * EE + EE);   // 2112 floats = 528 float4
constexpr int REC4 = REC / 4;              // 528
constexpr int OFF_S1 = 0, OFF_K1 = 1024, OFF_S2 = 1056, OFF_K2 = 2080;
constexpr int SK = EE + 4;   // 36: float2/float4-aligned row stride
constexpr int SP = EE + 1;   // 33: scalar row stride (2-way = free)

__device__ __forceinline__ float elu1(float x) {
    return x > 0.f ? x + 1.f : __expf(x);   // elu(x)+1
}

// ---------------- Kernel 1: per-chunk state sums -> ws -----------------------
// one block per (n,h,chunk); 512 threads (clean R6 version — no forced
// min-waves: spills cost 10x more than occupancy buys, see R7 post-mortem)
__global__ __launch_bounds__(512) void chunksum_kernel(
    const float* __restrict__ Kin, const float* __restrict__ Vin,
    const float* __restrict__ KLin, float* __restrict__ ws)
{
    __shared__ float K1n[CC][SK];
    __shared__ float K2n[CC][SK];
    __shared__ float Vs [CC][SK];

    const int b  = blockIdx.x;
    const int c  = b & (NCH - 1);
    const int nh = b >> 5;
    const int t  = threadIdx.x;
    const int lane = t & 31;
    const int grp  = t >> 5;    // 0..15

    // phase 1: feature map + normalize (half-wave per row)
    for (int r = grp; r < CC; r += 16) {
        const int l = c * CC + r;
        const int base = ((nh >> 3) * LL + l) * HH * EE + (nh & 7) * EE + lane;
        const float k    = Kin[base];
        const float v    = Vin[base];
        const float klen = KLin[(nh >> 3) * LL + l];
        const float f1 = elu1(k);
        const float k1v = f1 * klen;
        const float k2v = f1 * f1 * klen;
        float s1 = k1v, s2 = k2v;
        #pragma unroll
        for (int m = 1; m < 32; m <<= 1) {
            s1 += __shfl_xor(s1, m, 32);
            s2 += __shfl_xor(s2, m, 32);
        }
        K1n[r][lane] = k1v / s1;
        K2n[r][lane] = k2v / s2;
        Vs [r][lane] = v;
    }
    __syncthreads();

    // phase 2: S[e][d] = sum_j K[j][e]*V[j][d]; thread = (e = t>>4, 2 d's)
    // ascending-j order => bit-identical ws entries vs R5/R6/R7.
    const int e  = t >> 4;          // 0..31
    const int d0 = (t & 15) * 2;    // 0..30
    float a1x = 0.f, a1y = 0.f, a2x = 0.f, a2y = 0.f;
    float ks1 = 0.f, ks2 = 0.f;
    for (int j = 0; j < CC; ++j) {
        const float k1 = K1n[j][e];     // same-address broadcast, free
        const float k2 = K2n[j][e];
        const float2 v = *(const float2*)&Vs[j][d0];
        ks1 += k1; ks2 += k2;
        a1x += k1 * v.x; a1y += k1 * v.y;
        a2x += k2 * v.x; a2y += k2 * v.y;
    }
    float* wb = ws + (size_t)b * REC;
    *(float2*)&wb[OFF_S1 + e * EE + d0] = make_float2(a1x, a1y);
    *(float2*)&wb[OFF_S2 + e * EE + d0] = make_float2(a2x, a2y);
    if ((t & 15) == 0) {
        wb[OFF_K1 + e] = ks1;
        wb[OFF_K2 + e] = ks2;
    }
}

// ---------------- Kernel 2: exclusive prefix over chunks per (n,h) -----------
// register scan, proven in R5 (100us -> off the profile)
// grid = 16 groups x 11 blocks of 192 threads (192*11 == REC exactly)
__global__ __launch_bounds__(192) void prefix_kernel(float* __restrict__ ws)
{
    const int g = blockIdx.x / 11;
    const int e = (blockIdx.x % 11) * 192 + threadIdx.x;   // 0..2111
    float* base = ws + (size_t)g * NCH * REC + e;
    float v[NCH];
    #pragma unroll
    for (int c = 0; c < NCH; ++c) v[c] = base[(size_t)c * REC];
    float run = 0.f;
    #pragma unroll
    for (int c = 0; c < NCH; ++c) {
        const float x = v[c];
        base[(size_t)c * REC] = run;
        run += x;
    }
}

// ---------------- Kernel 3: band + linear + single store ---------------------
// one block per (n,h,chunk); 512 threads. Band: half-wave per row, scalar
// stride-33 (R5/R7-proven conflict-free) + ONLINE softmax (no sarr[10] ->
// no spill). Linear: 8-lane cluster per row, float4 (R6-proven
// conflict-free). launch_bounds(512,2): VGPR cap 256 — R7 showed forcing
// 8 waves/EU costs 187 MB of scratch spill traffic.
__global__ __launch_bounds__(512, 2) void fused_kernel(
    const float* __restrict__ Qin, const float* __restrict__ Kin,
    const float* __restrict__ Vin, const float* __restrict__ KLin,
    const float* __restrict__ W1, const float* __restrict__ W2,
    const float* __restrict__ W3, const float* __restrict__ ws,
    float* __restrict__ out)
{
    __shared__ float K1n[CC][SK];          // normalized K, float4-read rows
    __shared__ float K2n[CC][SK];
    __shared__ float Vs [CC + 9][SK];      // rows l0-9 .. l0+63
    __shared__ float Bnd[CC][SK];          // band partial (float4-aligned)
    // raw-K (band phase) and prefix state (linear phase): disjoint lifetimes
    __shared__ __align__(16) union {
        float kr[(CC + 9) * SP];           // 2409 floats
        float sp[REC];                     // 2112 floats, ws-record layout
    } U;

    const int b  = blockIdx.x;
    const int c  = b & (NCH - 1);
    const int nh = b >> 5;
    const int h  = nh & 7;
    const int n  = nh >> 3;
    const int l0 = c * CC;
    const int t  = threadIdx.x;
    const int lane = t & 31;
    const int grp  = t >> 5;       // 0..15

    // own exclusive-prefix record -> registers early (hides under A/B)
    const float4* wbv = (const float4*)(ws + (size_t)b * REC);
    const float4 s0 = wbv[t];                       // 512 of 528
    float4 s1 = {0.f, 0.f, 0.f, 0.f};
    if (t < REC4 - 512) s1 = wbv[512 + t];          // last 16

    // ---------------- Phase A: K/V staging + feature map + normalize ---------
    for (int r = grp; r < CC; r += 16) {
        const int l = l0 + r;
        const int base = ((n * LL + l) * HH + h) * EE + lane;
        const float k    = Kin[base];
        const float v    = Vin[base];
        const float klen = KLin[n * LL + l];
        const float f1 = elu1(k);
        const float k1v = f1 * klen;
        const float k2v = f1 * f1 * klen;
        float sk1 = k1v, sk2 = k2v;
        #pragma unroll
        for (int m = 1; m < 32; m <<= 1) {
            sk1 += __shfl_xor(sk1, m, 32);
            sk2 += __shfl_xor(sk2, m, 32);
        }
        K1n[r][lane] = k1v / sk1;
        K2n[r][lane] = k2v / sk2;
        Vs [9 + r][lane] = v;
        U.kr[(9 + r) * SP + lane] = k;
    }
    // previous 9 rows of raw K,V for the band window
    if (t < 9 * 32) {
        const int rr = t >> 5, ln = t & 31;
        const int l = l0 - 9 + rr;
        float kv = 0.f, vv = 0.f;
        if (l >= 0) {
            const int base = ((n * LL + l) * HH + h) * EE + ln;
            kv = Kin[base];
            vv = Vin[base];
        }
        U.kr[rr * SP + ln] = kv;
        Vs[rr][ln] = vv;
    }
    __syncthreads();

    // ---------------- Phase B: banded ONLINE softmax, half-wave per row ------
    {
        const float temp = 0.17677669529663687f;   // 1/sqrt(32)
        const float w1v = W1[h * EE + lane];
        for (int r = grp; r < CC; r += 16) {
            const int l = l0 + r;
            const float q = Qin[((n * LL + l) * HH + h) * EE + lane];
            float mx = -INFINITY, den = 0.f, sv = 0.f;
            #pragma unroll
            for (int jj = 0; jj < BWD; ++jj) {
                const int j = l - (BWD - 1) + jj;
                if (j >= 0) {                      // uniform per half-wave row
                    float p = q * U.kr[(r + jj) * SP + lane];   // 2-way, free
                    #pragma unroll
                    for (int m = 1; m < 32; m <<= 1) p += __shfl_xor(p, m, 32);
                    const float s  = p * temp;
                    const float mn = fmaxf(mx, s);
                    const float c1 = __expf(mx - mn);   // 0 on first iter
                    const float c2 = __expf(s - mn);
                    den = den * c1 + c2;
                    sv  = sv  * c1 + c2 * Vs[r + jj][lane];
                    mx = mn;
                }
            }
            Bnd[r][lane] = w1v * (sv / den);
        }
    }
    __syncthreads();   // all reads of U.kr done

    // publish own prefix record into U.sp (same layout as ws record)
    ((float4*)U.sp)[t] = s0;
    if (t < REC4 - 512) ((float4*)U.sp)[512 + t] = s1;
    __syncthreads();

    const float* S1p = U.sp + OFF_S1;
    const float* S2p = U.sp + OFF_S2;
    const float* k1p = U.sp + OFF_K1;
    const float* k2p = U.sp + OFF_K2;

    // ---------------- Phase C: 8-lane cluster per row, 4 features/lane -------
    const int r   = t >> 3;        // row 0..63
    const int sub = t & 7;
    const int d0  = sub * 4;
    const int l   = l0 + r;

    const float4 q4 = *(const float4*)&Qin[((n * LL + l) * HH + h) * EE + d0];
    float q1r[4], q2r[4];
    {
        const float f0 = elu1(q4.x), f1 = elu1(q4.y), f2 = elu1(q4.z), f3 = elu1(q4.w);
        float sq1 = f0 + f1 + f2 + f3;
        float sq2 = f0*f0 + f1*f1 + f2*f2 + f3*f3;
        sq1 += __shfl_xor(sq1, 1, 8); sq1 += __shfl_xor(sq1, 2, 8); sq1 += __shfl_xor(sq1, 4, 8);
        sq2 += __shfl_xor(sq2, 1, 8); sq2 += __shfl_xor(sq2, 2, 8); sq2 += __shfl_xor(sq2, 4, 8);
        const float i1 = 1.f / sq1, i2 = 1.f / sq2;
        q1r[0] = f0 * i1; q1r[1] = f1 * i1; q1r[2] = f2 * i1; q1r[3] = f3 * i1;
        q2r[0] = f0*f0 * i2; q2r[1] = f1*f1 * i2; q2r[2] = f2*f2 * i2; q2r[3] = f3*f3 * i2;
    }

    float acc1[4] = {0.f, 0.f, 0.f, 0.f};
    float acc2[4] = {0.f, 0.f, 0.f, 0.f};
    float den1 = 0.f, den2 = 0.f;

    // prefix contribution: q broadcast over cluster via width-8 shfl
    #pragma unroll
    for (int who = 0; who < 8; ++who) {
        #pragma unroll
        for (int i = 0; i < 4; ++i) {
            const int e = who * 4 + i;
            const float q1 = __shfl(q1r[i], who, 8);
            const float q2 = __shfl(q2r[i], who, 8);
            den1 += q1 * k1p[e];
            den2 += q2 * k2p[e];
            const float4 sa = *(const float4*)&S1p[e * EE + d0];   // broadcast
            const float4 ta = *(const float4*)&S2p[e * EE + d0];
            acc1[0] += q1 * sa.x; acc1[1] += q1 * sa.y;
            acc1[2] += q1 * sa.z; acc1[3] += q1 * sa.w;
            acc2[0] += q2 * ta.x; acc2[1] += q2 * ta.y;
            acc2[2] += q2 * ta.z; acc2[3] += q2 * ta.w;
        }
    }

    // intra-chunk causal: j uniform per iteration -> LDS broadcast, free
    for (int j = 0; j <= r; ++j) {
        const float4 ka = *(const float4*)&K1n[j][d0];
        const float4 la = *(const float4*)&K2n[j][d0];
        float p1 = q1r[0]*ka.x + q1r[1]*ka.y + q1r[2]*ka.z + q1r[3]*ka.w;
        float p2 = q2r[0]*la.x + q2r[1]*la.y + q2r[2]*la.z + q2r[3]*la.w;
        p1 += __shfl_xor(p1, 1, 8); p1 += __shfl_xor(p1, 2, 8); p1 += __shfl_xor(p1, 4, 8);
        p2 += __shfl_xor(p2, 1, 8); p2 += __shfl_xor(p2, 2, 8); p2 += __shfl_xor(p2, 4, 8);
        den1 += p1;
        den2 += p2;
        const float4 va = *(const float4*)&Vs[9 + j][d0];
        acc1[0] += p1 * va.x; acc1[1] += p1 * va.y;
        acc1[2] += p1 * va.z; acc1[3] += p1 * va.w;
        acc2[0] += p2 * va.x; acc2[1] += p2 * va.y;
        acc2[2] += p2 * va.z; acc2[3] += p2 * va.w;
    }

    const float z1 = 1.f / (den1 + EPSF);
    const float z2 = 1.f / (den2 + EPSF);
    const float4 w2 = *(const float4*)&W2[h * EE + d0];
    const float4 w3 = *(const float4*)&W3[h * EE + d0];
    const float4 bd = *(const float4*)&Bnd[r][d0];   // one-off read
    float4 o;
    o.x = bd.x + w2.x * acc1[0] * z1 + w3.x * acc2[0] * z2;
    o.y = bd.y + w2.y * acc1[1] * z1 + w3.y * acc2[1] * z2;
    o.z = bd.z + w2.z * acc1[2] * z1 + w3.z * acc2[2] * z2;
    o.w = bd.w + w2.w * acc1[3] * z1 + w3.w * acc2[3] * z2;
    *(float4*)&out[((n * LL + l) * HH + h) * EE + d0] = o;
}

extern "C" void kernel_launch(void* const* d_in, const int* in_sizes, int n_in,
                              void* d_out, int out_size, void* d_ws, size_t ws_size,
                              hipStream_t stream)
{
    const float* Q  = (const float*)d_in[0];
    const float* K  = (const float*)d_in[1];
    const float* V  = (const float*)d_in[2];
    const float* KL = (const float*)d_in[3];
    const float* W1 = (const float*)d_in[4];
    const float* W2 = (const float*)d_in[5];
    const float* W3 = (const float*)d_in[6];
    float* out = (float*)d_out;
    float* ws  = (float*)d_ws;   // uses NB*REC*4 = ~4.3 MB of scratch

    chunksum_kernel<<<NB,           512, 0, stream>>>(K, V, KL, ws);
    prefix_kernel  <<<NN * HH * 11, 192, 0, stream>>>(ws);
    fused_kernel   <<<NB,           512, 0, stream>>>(Q, K, V, KL, W1, W2, W3, ws, out);
}

// Round 9
// 113.759 us; speedup vs baseline: 1.7483x; 1.0893x over previous
//
#include <hip/hip_runtime.h>
#include <cmath>

// Problem constants (fixed by setup_inputs)
constexpr int NN = 2;       // batch
constexpr int LL = 2048;    // sequence
constexpr int HH = 8;       // heads
constexpr int EE = 32;      // feature dim == value dim
constexpr int CC = 32;      // chunk length (R9: halved -> 4 blocks/CU, half triangle work)
constexpr int NCH = LL / CC;       // 64 chunks per (n,h)
constexpr int NB  = NN * HH * NCH; // 1024 blocks
constexpr int BWD = 10;     // softmax bandwidth
constexpr float EPSF = 1e-6f;
// ws record per chunk: S1[32*32], k1[32], S2[32*32], k2[32] (floats)
constexpr int REC  = 2 * (EE * EE + EE);   // 2112 floats = 528 float4
constexpr int REC4 = REC / 4;              // 528
constexpr int OFF_S1 = 0, OFF_K1 = 1024, OFF_S2 = 1056, OFF_K2 = 2080;
constexpr int SK = EE + 4;   // 36: float4-aligned row stride, %32==4 (conflict-free f4)
constexpr int SP = EE + 1;   // 33: scalar row stride (2-way = free)

// NOTE (derivation, R8 post-mortem): key_lengths CANCELS — K is normalized
// over E after the klen multiply and klen is constant over E. And with
// Qf=elu1(q), Kf=elu1(k):  Q1n.K1n = qi1*ki1*(Qf.Kf),  Q2n.K2n =
// qi2*ki2*(Qf.Kf)^2  where qi1=1/sum(Qf) etc. One Kf array serves both
// branches; t=qf*kf gives both dots via sum(t), sum(t^2).

__device__ __forceinline__ float elu1(float x) {
    return x > 0.f ? x + 1.f : __expf(x);   // elu(x)+1
}

// ---------------- Kernel 1: per-chunk state sums -> ws -----------------------
// one block per (n,h,chunk); 256 threads, CC=32
__global__ __launch_bounds__(256) void chunksum_kernel(
    const float* __restrict__ Kin, const float* __restrict__ Vin,
    float* __restrict__ ws)
{
    __shared__ float K1n[CC][SK];
    __shared__ float K2n[CC][SK];
    __shared__ float Vs [CC][SK];

    const int b  = blockIdx.x;
    const int c  = b & (NCH - 1);
    const int nh = b >> 6;
    const int t  = threadIdx.x;
    const int lane = t & 31;
    const int grp  = t >> 5;    // 0..7

    // phase 1: feature map + normalize (half-wave per row; klen cancels)
    for (int r = grp; r < CC; r += 8) {
        const int l = c * CC + r;
        const int base = ((nh >> 3) * LL + l) * HH * EE + (nh & 7) * EE + lane;
        const float k = Kin[base];
        const float v = Vin[base];
        const float f1 = elu1(k);
        const float f2 = f1 * f1;
        float s1 = f1, s2 = f2;
        #pragma unroll
        for (int m = 1; m < 32; m <<= 1) {
            s1 += __shfl_xor(s1, m, 32);
            s2 += __shfl_xor(s2, m, 32);
        }
        K1n[r][lane] = f1 / s1;
        K2n[r][lane] = f2 / s2;
        Vs [r][lane] = v;
    }
    __syncthreads();

    // phase 2: S[e][d] = sum_j K[j][e]*V[j][d]; thread = (e = t>>3, 4 d's)
    const int e  = t >> 3;          // 0..31
    const int d0 = (t & 7) * 4;     // 0..28
    float4 a1 = {0.f, 0.f, 0.f, 0.f};
    float4 a2 = {0.f, 0.f, 0.f, 0.f};
    float ks1 = 0.f, ks2 = 0.f;
    for (int j = 0; j < CC; ++j) {
        const float k1 = K1n[j][e];     // multicast, free
        const float k2 = K2n[j][e];
        const float4 v = *(const float4*)&Vs[j][d0];
        ks1 += k1; ks2 += k2;
        a1.x += k1 * v.x; a1.y += k1 * v.y; a1.z += k1 * v.z; a1.w += k1 * v.w;
        a2.x += k2 * v.x; a2.y += k2 * v.y; a2.z += k2 * v.z; a2.w += k2 * v.w;
    }
    float* wb = ws + (size_t)b * REC;
    *(float4*)&wb[OFF_S1 + e * EE + d0] = a1;
    *(float4*)&wb[OFF_S2 + e * EE + d0] = a2;
    if ((t & 7) == 0) {
        wb[OFF_K1 + e] = ks1;
        wb[OFF_K2 + e] = ks2;
    }
}

// ---------------- Kernel 2: exclusive prefix over chunks per (n,h) -----------
// register scan (R5-proven), extended to NCH=64 as two 32-deep passes.
// grid = 16 groups x 11 blocks of 192 threads (192*11 == REC exactly)
__global__ __launch_bounds__(192) void prefix_kernel(float* __restrict__ ws)
{
    const int g = blockIdx.x / 11;
    const int e = (blockIdx.x % 11) * 192 + threadIdx.x;   // 0..2111
    float* base = ws + (size_t)g * NCH * REC + e;
    float run = 0.f;
    {
        float v[32];
        #pragma unroll
        for (int c = 0; c < 32; ++c) v[c] = base[(size_t)c * REC];
        #pragma unroll
        for (int c = 0; c < 32; ++c) {
            const float x = v[c];
            base[(size_t)c * REC] = run;
            run += x;
        }
    }
    {
        float v[32];
        #pragma unroll
        for (int c = 0; c < 32; ++c) v[c] = base[(size_t)(32 + c) * REC];
        #pragma unroll
        for (int c = 0; c < 32; ++c) {
            const float x = v[c];
            base[(size_t)(32 + c) * REC] = run;
            run += x;
        }
    }
}

// ---------------- Kernel 3: band + linear + single store ---------------------
// one block per (n,h,chunk); 256 threads, CC=32, LDS ~28 KB -> grid gives
// 4 independent blocks/CU (unaligned barriers -> latency overlap).
// Band: half-wave/row scalar (proven conflict-free) + online softmax.
// Linear: 8-lane cluster/row, factorized single-Kf dots.
__global__ __launch_bounds__(256) void fused_kernel(
    const float* __restrict__ Qin, const float* __restrict__ Kin,
    const float* __restrict__ Vin,
    const float* __restrict__ W1, const float* __restrict__ W2,
    const float* __restrict__ W3, const float* __restrict__ ws,
    float* __restrict__ out)
{
    __shared__ float Kf [CC][SK];          // elu1(K), f4 rows
    __shared__ float Vs [CC + 9][SK];      // rows l0-9 .. l0+31
    __shared__ float Qf [CC][SK];          // elu1(Q), f4 + scalar-bcast reads
    __shared__ float Bnd[CC][SK];          // band partial (f4-aligned)
    __shared__ float ki1[CC], ki2[CC], qi1[CC], qi2[CC];
    // raw-K (band) and prefix state (linear): disjoint lifetimes
    __shared__ __align__(16) union {
        float kr[(CC + 9) * SP];           // 1353 floats
        float sp[REC];                     // 2112 floats, ws-record layout
    } U;

    const int b  = blockIdx.x;
    const int c  = b & (NCH - 1);
    const int nh = b >> 6;
    const int h  = nh & 7;
    const int n  = nh >> 3;
    const int l0 = c * CC;
    const int t  = threadIdx.x;
    const int lane = t & 31;
    const int grp  = t >> 5;       // 0..7

    // own exclusive-prefix record -> registers early (hides under A/B)
    const float4* wbv = (const float4*)(ws + (size_t)b * REC);
    const float4 s0 = wbv[t];
    const float4 s1 = wbv[256 + t];
    float4 s2 = {0.f, 0.f, 0.f, 0.f};
    if (t < REC4 - 512) s2 = wbv[512 + t];          // last 16

    // ---------------- Phase A: staging + feature maps + row sums -------------
    for (int r = grp; r < CC; r += 8) {
        const int l = l0 + r;
        const int base = ((n * LL + l) * HH + h) * EE + lane;
        const float k = Kin[base];
        const float v = Vin[base];
        const float q = Qin[base];
        const float fk = elu1(k), fk2 = fk * fk;
        const float fq = elu1(q), fq2 = fq * fq;
        float sk1 = fk, sk2 = fk2, sq1 = fq, sq2 = fq2;
        #pragma unroll
        for (int m = 1; m < 32; m <<= 1) {
            sk1 += __shfl_xor(sk1, m, 32);
            sk2 += __shfl_xor(sk2, m, 32);
            sq1 += __shfl_xor(sq1, m, 32);
            sq2 += __shfl_xor(sq2, m, 32);
        }
        Kf[r][lane] = fk;
        Qf[r][lane] = fq;
        Vs[9 + r][lane] = v;
        U.kr[(9 + r) * SP + lane] = k;
        if (lane == 0) {
            ki1[r] = 1.f / sk1; ki2[r] = 1.f / sk2;
            qi1[r] = 1.f / sq1; qi2[r] = 1.f / sq2;
        }
    }
    // previous 9 rows of raw K,V for the band window
    for (int idx = t; idx < 9 * 32; idx += 256) {
        const int rr = idx >> 5, ln = idx & 31;
        const int l = l0 - 9 + rr;
        float kv = 0.f, vv = 0.f;
        if (l >= 0) {
            const int base = ((n * LL + l) * HH + h) * EE + ln;
            kv = Kin[base];
            vv = Vin[base];
        }
        U.kr[rr * SP + ln] = kv;
        Vs[rr][ln] = vv;
    }
    __syncthreads();

    // ---------------- Phase B: banded ONLINE softmax, half-wave per row ------
    {
        const float temp = 0.17677669529663687f;   // 1/sqrt(32)
        const float w1v = W1[h * EE + lane];
        for (int r = grp; r < CC; r += 8) {
            const int l = l0 + r;
            const float q = Qin[((n * LL + l) * HH + h) * EE + lane];
            float mx = -INFINITY, den = 0.f, sv = 0.f;
            #pragma unroll
            for (int jj = 0; jj < BWD; ++jj) {
                const int j = l - (BWD - 1) + jj;
                if (j >= 0) {                      // uniform per half-wave row
                    float p = q * U.kr[(r + jj) * SP + lane];   // 2-way, free
                    #pragma unroll
                    for (int m = 1; m < 32; m <<= 1) p += __shfl_xor(p, m, 32);
                    const float s  = p * temp;
                    const float mn = fmaxf(mx, s);
                    const float c1 = __expf(mx - mn);   // 0 on first iter
                    const float c2 = __expf(s - mn);
                    den = den * c1 + c2;
                    sv  = sv  * c1 + c2 * Vs[r + jj][lane];
                    mx = mn;
                }
            }
            Bnd[r][lane] = w1v * (sv / den);
        }
    }
    __syncthreads();   // all reads of U.kr done

    // publish own prefix record into U.sp (same layout as ws record)
    ((float4*)U.sp)[t]       = s0;
    ((float4*)U.sp)[256 + t] = s1;
    if (t < REC4 - 512) ((float4*)U.sp)[512 + t] = s2;
    __syncthreads();

    const float* S1p = U.sp + OFF_S1;
    const float* S2p = U.sp + OFF_S2;
    const float* k1p = U.sp + OFF_K1;
    const float* k2p = U.sp + OFF_K2;

    // ---------------- Phase C: 8-lane cluster per row, factorized ------------
    const int r   = t >> 3;        // row 0..31
    const int sub = t & 7;
    const int d0  = sub * 4;
    const int l   = l0 + r;

    const float qi1v = qi1[r];     // multicast
    const float qi2v = qi2[r];
    const float4 qf4 = *(const float4*)&Qf[r][d0];

    float a1[4] = {0.f, 0.f, 0.f, 0.f};   // unscaled (x qi1 at end)
    float a2[4] = {0.f, 0.f, 0.f, 0.f};
    float dp1 = 0.f, dp2 = 0.f;

    // prefix contribution: a1 += Qf[e] * S1p[e][:], a2 += Qf[e]^2 * S2p[e][:]
    #pragma unroll 4
    for (int e = 0; e < EE; ++e) {
        const float tq  = Qf[r][e];            // multicast
        const float tq2 = tq * tq;
        dp1 += tq  * k1p[e];
        dp2 += tq2 * k2p[e];
        const float4 sa = *(const float4*)&S1p[e * EE + d0];
        const float4 ta = *(const float4*)&S2p[e * EE + d0];
        a1[0] += tq  * sa.x; a1[1] += tq  * sa.y; a1[2] += tq  * sa.z; a1[3] += tq  * sa.w;
        a2[0] += tq2 * ta.x; a2[1] += tq2 * ta.y; a2[2] += tq2 * ta.z; a2[3] += tq2 * ta.w;
    }

    // intra-chunk causal: one Kf read serves both branches
    for (int j = 0; j <= r; ++j) {
        const float4 kf = *(const float4*)&Kf[j][d0];
        const float t0 = qf4.x * kf.x, t1 = qf4.y * kf.y;
        const float t2 = qf4.z * kf.z, t3 = qf4.w * kf.w;
        float u1 = (t0 + t1) + (t2 + t3);
        float u2 = ((t0 * t0 + t1 * t1) + (t2 * t2 + t3 * t3));
        u1 += __shfl_xor(u1, 1, 8); u1 += __shfl_xor(u1, 2, 8); u1 += __shfl_xor(u1, 4, 8);
        u2 += __shfl_xor(u2, 1, 8); u2 += __shfl_xor(u2, 2, 8); u2 += __shfl_xor(u2, 4, 8);
        const float p1 = u1 * ki1[j];          // multicast
        const float p2 = u2 * ki2[j];
        dp1 += p1;
        dp2 += p2;
        const float4 va = *(const float4*)&Vs[9 + j][d0];
        a1[0] += p1 * va.x; a1[1] += p1 * va.y; a1[2] += p1 * va.z; a1[3] += p1 * va.w;
        a2[0] += p2 * va.x; a2[1] += p2 * va.y; a2[2] += p2 * va.z; a2[3] += p2 * va.w;
    }

    const float z1 = qi1v / (qi1v * dp1 + EPSF);   // qi1 * 1/(qi1*dp1+eps)
    const float z2 = qi2v / (qi2v * dp2 + EPSF);
    const float4 w2 = *(const float4*)&W2[h * EE + d0];
    const float4 w3 = *(const float4*)&W3[h * EE + d0];
    const float4 bd = *(const float4*)&Bnd[r][d0];
    float4 o;
    o.x = bd.x + w2.x * a1[0] * z1 + w3.x * a2[0] * z2;
    o.y = bd.y + w2.y * a1[1] * z1 + w3.y * a2[1] * z2;
    o.z = bd.z + w2.z * a1[2] * z1 + w3.z * a2[2] * z2;
    o.w = bd.w + w2.w * a1[3] * z1 + w3.w * a2[3] * z2;
    *(float4*)&out[((n * LL + l) * HH + h) * EE + d0] = o;
}

extern "C" void kernel_launch(void* const* d_in, const int* in_sizes, int n_in,
                              void* d_out, int out_size, void* d_ws, size_t ws_size,
                              hipStream_t stream)
{
    const float* Q  = (const float*)d_in[0];
    const float* K  = (const float*)d_in[1];
    const float* V  = (const float*)d_in[2];
    // d_in[3] = key_lengths: mathematically cancels (normalization over E)
    const float* W1 = (const float*)d_in[4];
    const float* W2 = (const float*)d_in[5];
    const float* W3 = (const float*)d_in[6];
    float* out = (float*)d_out;
    float* ws  = (float*)d_ws;   // uses NB*REC*4 = ~8.7 MB of scratch

    chunksum_kernel<<<NB,           256, 0, stream>>>(K, V, ws);
    prefix_kernel  <<<NN * HH * 11, 192, 0, stream>>>(ws);
    fused_kernel   <<<NB,           256, 0, stream>>>(Q, K, V, W1, W2, W3, ws, out);
}

// Round 10
// 106.669 us; speedup vs baseline: 1.8645x; 1.0665x over previous
//
#include <hip/hip_runtime.h>
#include <cmath>

// Problem constants (fixed by setup_inputs)
constexpr int NN = 2;       // batch
constexpr int LL = 2048;    // sequence
constexpr int HH = 8;       // heads
constexpr int EE = 32;      // feature dim == value dim
constexpr int CC = 32;      // chunk length (4 blocks/CU, half triangle work)
constexpr int NCH = LL / CC;       // 64 chunks per (n,h)
constexpr int NB  = NN * HH * NCH; // 1024 blocks
constexpr int BWD = 10;     // softmax bandwidth
constexpr float EPSF = 1e-6f;
// ws record per chunk: S1[32*32], k1[32], S2[32*32], k2[32] (floats)
constexpr int REC  = 2 * (EE * EE + EE);   // 2112 floats = 528 float4
constexpr int REC4 = REC / 4;              // 528
constexpr int OFF_S1 = 0, OFF_K1 = 1024, OFF_S2 = 1056, OFF_K2 = 2080;
constexpr int SK = EE + 4;   // 36: float4-aligned row stride (144 B, 16B-aligned)

// key_lengths cancels (normalized over E after a per-row constant multiply).
// Factorization: with Qf=elu1(q), Kf=elu1(k): Q1n.K1n = qi1*ki1*(Qf.Kf),
// Q2n.K2n = qi2*ki2*sum((qf*kf)^2) — one Kf array serves both branches.

__device__ __forceinline__ float elu1(float x) {
    return x > 0.f ? x + 1.f : __expf(x);   // elu(x)+1
}

// ---------------- Kernel 1: per-chunk state sums -> ws -----------------------
// one block per (n,h,chunk); 256 threads, CC=32  (unchanged from R9-passing)
__global__ __launch_bounds__(256) void chunksum_kernel(
    const float* __restrict__ Kin, const float* __restrict__ Vin,
    float* __restrict__ ws)
{
    __shared__ float K1n[CC][SK];
    __shared__ float K2n[CC][SK];
    __shared__ float Vs [CC][SK];

    const int b  = blockIdx.x;
    const int c  = b & (NCH - 1);
    const int nh = b >> 6;
    const int t  = threadIdx.x;
    const int lane = t & 31;
    const int grp  = t >> 5;    // 0..7

    for (int r = grp; r < CC; r += 8) {
        const int l = c * CC + r;
        const int base = ((nh >> 3) * LL + l) * HH * EE + (nh & 7) * EE + lane;
        const float k = Kin[base];
        const float v = Vin[base];
        const float f1 = elu1(k);
        const float f2 = f1 * f1;
        float s1 = f1, s2 = f2;
        #pragma unroll
        for (int m = 1; m < 32; m <<= 1) {
            s1 += __shfl_xor(s1, m, 32);
            s2 += __shfl_xor(s2, m, 32);
        }
        K1n[r][lane] = f1 / s1;
        K2n[r][lane] = f2 / s2;
        Vs [r][lane] = v;
    }
    __syncthreads();

    const int e  = t >> 3;          // 0..31
    const int d0 = (t & 7) * 4;     // 0..28
    float4 a1 = {0.f, 0.f, 0.f, 0.f};
    float4 a2 = {0.f, 0.f, 0.f, 0.f};
    float ks1 = 0.f, ks2 = 0.f;
    for (int j = 0; j < CC; ++j) {
        const float k1 = K1n[j][e];     // multicast, free
        const float k2 = K2n[j][e];
        const float4 v = *(const float4*)&Vs[j][d0];
        ks1 += k1; ks2 += k2;
        a1.x += k1 * v.x; a1.y += k1 * v.y; a1.z += k1 * v.z; a1.w += k1 * v.w;
        a2.x += k2 * v.x; a2.y += k2 * v.y; a2.z += k2 * v.z; a2.w += k2 * v.w;
    }
    float* wb = ws + (size_t)b * REC;
    *(float4*)&wb[OFF_S1 + e * EE + d0] = a1;
    *(float4*)&wb[OFF_S2 + e * EE + d0] = a2;
    if ((t & 7) == 0) {
        wb[OFF_K1 + e] = ks1;
        wb[OFF_K2 + e] = ks2;
    }
}

// ---------------- Kernel 2: exclusive prefix over chunks per (n,h) -----------
// register scan (R5-proven), NCH=64 as two 32-deep passes.
__global__ __launch_bounds__(192) void prefix_kernel(float* __restrict__ ws)
{
    const int g = blockIdx.x / 11;
    const int e = (blockIdx.x % 11) * 192 + threadIdx.x;   // 0..2111
    float* base = ws + (size_t)g * NCH * REC + e;
    float run = 0.f;
    {
        float v[32];
        #pragma unroll
        for (int c = 0; c < 32; ++c) v[c] = base[(size_t)c * REC];
        #pragma unroll
        for (int c = 0; c < 32; ++c) {
            const float x = v[c];
            base[(size_t)c * REC] = run;
            run += x;
        }
    }
    {
        float v[32];
        #pragma unroll
        for (int c = 0; c < 32; ++c) v[c] = base[(size_t)(32 + c) * REC];
        #pragma unroll
        for (int c = 0; c < 32; ++c) {
            const float x = v[c];
            base[(size_t)(32 + c) * REC] = run;
            run += x;
        }
    }
}

// ---------------- Kernel 3: band + linear + single store ---------------------
// one block per (n,h,chunk); 256 threads. Band REWORKED (R10): 8-lane
// cluster per row, ALIGNED stride-36 float4 Kr/Vs reads + online softmax
// -> 5 DS insts per 8 scores (was ~24) and a 4x shorter serial chain.
// Output of band stays in registers (same (r,d-quad) mapping as Phase C)
// -> Bnd LDS array deleted. R6's 327K conflicts were from MISALIGNED f4
// on stride-33, not from cluster dots; all f4 here is 16B-aligned.
__global__ __launch_bounds__(256) void fused_kernel(
    const float* __restrict__ Qin, const float* __restrict__ Kin,
    const float* __restrict__ Vin,
    const float* __restrict__ W1, const float* __restrict__ W2,
    const float* __restrict__ W3, const float* __restrict__ ws,
    float* __restrict__ out)
{
    __shared__ float Kf [CC][SK];          // elu1(K), f4 rows
    __shared__ float Vs [CC + 9][SK];      // rows l0-9 .. l0+31
    __shared__ float Qf [CC][SK];          // elu1(Q), scalar-bcast reads (e-loop)
    __shared__ float ki1[CC], ki2[CC], qi1[CC], qi2[CC];
    // raw-K (band) and prefix state (linear): disjoint lifetimes
    __shared__ __align__(16) union {
        float kr[(CC + 9) * SK];           // 1476 floats, f4-aligned rows
        float sp[REC];                     // 2112 floats, ws-record layout
    } U;

    const int b  = blockIdx.x;
    const int c  = b & (NCH - 1);
    const int nh = b >> 6;
    const int h  = nh & 7;
    const int n  = nh >> 3;
    const int l0 = c * CC;
    const int t  = threadIdx.x;
    const int lane = t & 31;
    const int grp  = t >> 5;       // 0..7

    // own exclusive-prefix record -> registers early (hides under A/B)
    const float4* wbv = (const float4*)(ws + (size_t)b * REC);
    const float4 s0 = wbv[t];
    const float4 s1 = wbv[256 + t];
    float4 s2 = {0.f, 0.f, 0.f, 0.f};
    if (t < REC4 - 512) s2 = wbv[512 + t];          // last 16

    // ---------------- Phase A: staging + feature maps + row sums -------------
    for (int r = grp; r < CC; r += 8) {
        const int l = l0 + r;
        const int base = ((n * LL + l) * HH + h) * EE + lane;
        const float k = Kin[base];
        const float v = Vin[base];
        const float q = Qin[base];
        const float fk = elu1(k), fk2 = fk * fk;
        const float fq = elu1(q), fq2 = fq * fq;
        float sk1 = fk, sk2 = fk2, sq1 = fq, sq2 = fq2;
        #pragma unroll
        for (int m = 1; m < 32; m <<= 1) {
            sk1 += __shfl_xor(sk1, m, 32);
            sk2 += __shfl_xor(sk2, m, 32);
            sq1 += __shfl_xor(sq1, m, 32);
            sq2 += __shfl_xor(sq2, m, 32);
        }
        Kf[r][lane] = fk;
        Qf[r][lane] = fq;
        Vs[9 + r][lane] = v;
        U.kr[(9 + r) * SK + lane] = k;
        if (lane == 0) {
            ki1[r] = 1.f / sk1; ki2[r] = 1.f / sk2;
            qi1[r] = 1.f / sq1; qi2[r] = 1.f / sq2;
        }
    }
    // previous 9 rows of raw K,V for the band window
    for (int idx = t; idx < 9 * 32; idx += 256) {
        const int rr = idx >> 5, ln = idx & 31;
        const int l = l0 - 9 + rr;
        float kv = 0.f, vv = 0.f;
        if (l >= 0) {
            const int base = ((n * LL + l) * HH + h) * EE + ln;
            kv = Kin[base];
            vv = Vin[base];
        }
        U.kr[rr * SK + ln] = kv;
        Vs[rr][ln] = vv;
    }

    // cluster identity for phases B and C
    const int r   = t >> 3;        // row 0..31
    const int sub = t & 7;
    const int d0  = sub * 4;
    const int l   = l0 + r;

    // raw Q quad in registers (serves band dot AND, via elu1, Phase C)
    const float4 q4 = *(const float4*)&Qin[((n * LL + l) * HH + h) * EE + d0];
    __syncthreads();

    // ---------------- Phase B: banded ONLINE softmax, cluster f4 -------------
    float bnd[4];
    {
        const float temp = 0.17677669529663687f;   // 1/sqrt(32)
        float mx = -INFINITY, den = 0.f;
        float sv0 = 0.f, sv1 = 0.f, sv2 = 0.f, sv3 = 0.f;
        #pragma unroll
        for (int jj = 0; jj < BWD; ++jj) {
            const int j = l - (BWD - 1) + jj;   // global key row
            if (j >= 0) {                        // uniform per 8-lane row group
                const float4 k4 = *(const float4*)&U.kr[(r + jj) * SK + d0];
                float p = q4.x*k4.x + q4.y*k4.y + q4.z*k4.z + q4.w*k4.w;
                p += __shfl_xor(p, 1, 8); p += __shfl_xor(p, 2, 8); p += __shfl_xor(p, 4, 8);
                const float s  = p * temp;
                const float mn = fmaxf(mx, s);
                const float c1 = __expf(mx - mn);   // 0 on first iter
                const float c2 = __expf(s - mn);
                const float4 v4 = *(const float4*)&Vs[r + jj][d0];
                den = den * c1 + c2;
                sv0 = sv0 * c1 + c2 * v4.x;
                sv1 = sv1 * c1 + c2 * v4.y;
                sv2 = sv2 * c1 + c2 * v4.z;
                sv3 = sv3 * c1 + c2 * v4.w;
                mx = mn;
            }
        }
        const float inv = 1.f / den;
        const float4 w1 = *(const float4*)&W1[h * EE + d0];
        bnd[0] = w1.x * sv0 * inv; bnd[1] = w1.y * sv1 * inv;
        bnd[2] = w1.z * sv2 * inv; bnd[3] = w1.w * sv3 * inv;
    }
    __syncthreads();   // all reads of U.kr done

    // publish own prefix record into U.sp (same layout as ws record)
    ((float4*)U.sp)[t]       = s0;
    ((float4*)U.sp)[256 + t] = s1;
    if (t < REC4 - 512) ((float4*)U.sp)[512 + t] = s2;
    __syncthreads();

    const float* S1p = U.sp + OFF_S1;
    const float* S2p = U.sp + OFF_S2;
    const float* k1p = U.sp + OFF_K1;
    const float* k2p = U.sp + OFF_K2;

    // ---------------- Phase C: 8-lane cluster per row, factorized ------------
    const float qi1v = qi1[r];     // multicast
    const float qi2v = qi2[r];
    float4 qf4;                    // elu1(q) from registers (no LDS read)
    qf4.x = elu1(q4.x); qf4.y = elu1(q4.y);
    qf4.z = elu1(q4.z); qf4.w = elu1(q4.w);

    float a1[4] = {0.f, 0.f, 0.f, 0.f};   // unscaled (x qi at end)
    float a2[4] = {0.f, 0.f, 0.f, 0.f};
    float dp1 = 0.f, dp2 = 0.f;

    // prefix contribution: a1 += Qf[e]*S1p[e][:], a2 += Qf[e]^2*S2p[e][:]
    #pragma unroll 4
    for (int e = 0; e < EE; ++e) {
        const float tq  = Qf[r][e];            // multicast
        const float tq2 = tq * tq;
        dp1 += tq  * k1p[e];
        dp2 += tq2 * k2p[e];
        const float4 sa = *(const float4*)&S1p[e * EE + d0];
        const float4 ta = *(const float4*)&S2p[e * EE + d0];
        a1[0] += tq  * sa.x; a1[1] += tq  * sa.y; a1[2] += tq  * sa.z; a1[3] += tq  * sa.w;
        a2[0] += tq2 * ta.x; a2[1] += tq2 * ta.y; a2[2] += tq2 * ta.z; a2[3] += tq2 * ta.w;
    }

    // intra-chunk causal: one Kf read serves both branches
    for (int j = 0; j <= r; ++j) {
        const float4 kf = *(const float4*)&Kf[j][d0];
        const float t0 = qf4.x * kf.x, t1 = qf4.y * kf.y;
        const float t2 = qf4.z * kf.z, t3 = qf4.w * kf.w;
        float u1 = (t0 + t1) + (t2 + t3);
        float u2 = ((t0 * t0 + t1 * t1) + (t2 * t2 + t3 * t3));
        u1 += __shfl_xor(u1, 1, 8); u1 += __shfl_xor(u1, 2, 8); u1 += __shfl_xor(u1, 4, 8);
        u2 += __shfl_xor(u2, 1, 8); u2 += __shfl_xor(u2, 2, 8); u2 += __shfl_xor(u2, 4, 8);
        const float p1 = u1 * ki1[j];          // multicast
        const float p2 = u2 * ki2[j];
        dp1 += p1;
        dp2 += p2;
        const float4 va = *(const float4*)&Vs[9 + j][d0];
        a1[0] += p1 * va.x; a1[1] += p1 * va.y; a1[2] += p1 * va.z; a1[3] += p1 * va.w;
        a2[0] += p2 * va.x; a2[1] += p2 * va.y; a2[2] += p2 * va.z; a2[3] += p2 * va.w;
    }

    const float z1 = qi1v / (qi1v * dp1 + EPSF);
    const float z2 = qi2v / (qi2v * dp2 + EPSF);
    const float4 w2 = *(const float4*)&W2[h * EE + d0];
    const float4 w3 = *(const float4*)&W3[h * EE + d0];
    float4 o;
    o.x = bnd[0] + w2.x * a1[0] * z1 + w3.x * a2[0] * z2;
    o.y = bnd[1] + w2.y * a1[1] * z1 + w3.y * a2[1] * z2;
    o.z = bnd[2] + w2.z * a1[2] * z1 + w3.z * a2[2] * z2;
    o.w = bnd[3] + w2.w * a1[3] * z1 + w3.w * a2[3] * z2;
    *(float4*)&out[((n * LL + l) * HH + h) * EE + d0] = o;
}

extern "C" void kernel_launch(void* const* d_in, const int* in_sizes, int n_in,
                              void* d_out, int out_size, void* d_ws, size_t ws_size,
                              hipStream_t stream)
{
    const float* Q  = (const float*)d_in[0];
    const float* K  = (const float*)d_in[1];
    const float* V  = (const float*)d_in[2];
    // d_in[3] = key_lengths: cancels mathematically (normalization over E)
    const float* W1 = (const float*)d_in[4];
    const float* W2 = (const float*)d_in[5];
    const float* W3 = (const float*)d_in[6];
    float* out = (float*)d_out;
    float* ws  = (float*)d_ws;   // uses NB*REC*4 = ~8.7 MB of scratch

    chunksum_kernel<<<NB,           256, 0, stream>>>(K, V, ws);
    prefix_kernel  <<<NN * HH * 11, 192, 0, stream>>>(ws);
    fused_kernel   <<<NB,           256, 0, stream>>>(Q, K, V, W1, W2, W3, ws, out);
}